// Round 8
// baseline (12786.380 us; speedup 1.0000x reference)
//
#include <hip/hip_runtime.h>
#include <hip/hip_fp16.h>
#include <stdint.h>

// LSTM policy rollout, weight-resident via explicit AGPR placement.
// 256 blocks x 1024 threads, 1 block/CU (LDS 140 KB). Each of 16 waves owns
// 3 gate rows: 2 rows in AGPRs (inline-asm "a" class, unspillable) + 1 in LDS.
// Grid sync = single atomic counter, tid0-only publish + poll (256 pollers
// total, not 65K — the per-block-flag barrier's poll storm was 43 us/step).

#define HID    4096
#define CTX    1024
#define NSTEPS 256
#define NBLK   256
#define TPB    1024
#define WAVES  16
#define HROWS  16          // h rows per block
#define GROWS  48          // gate rows per block
#define RPW    3           // rows per wave (2 AGPR + 1 LDS)
#define NCH    8           // column chunks of 512

typedef _Float16 h2 __attribute__((ext_vector_type(2)));

__device__ __forceinline__ float fdot2f(uint32_t a, uint32_t b, float c) {
#if __has_builtin(__builtin_amdgcn_fdot2)
  return __builtin_amdgcn_fdot2(__builtin_bit_cast(h2, a),
                                __builtin_bit_cast(h2, b), c, false);
#else
  h2 x = __builtin_bit_cast(h2, a), y = __builtin_bit_cast(h2, b);
  return c + (float)x[0]*(float)y[0] + (float)x[1]*(float)y[1];
#endif
}
__device__ __forceinline__ uint32_t pkf16(float x, float y) {
  h2 v; v[0] = (_Float16)x; v[1] = (_Float16)y;
  return __builtin_bit_cast(uint32_t, v);
}
__device__ __forceinline__ uint4 cvt8(const float* p) {
  return make_uint4(pkf16(p[0],p[1]), pkf16(p[2],p[3]),
                    pkf16(p[4],p[5]), pkf16(p[6],p[7]));
}
__device__ __forceinline__ float dot4(float acc, uint4 a, uint4 b) {
  acc = fdot2f(a.x, b.x, acc); acc = fdot2f(a.y, b.y, acc);
  acc = fdot2f(a.z, b.z, acc); acc = fdot2f(a.w, b.w, acc);
  return acc;
}
// AGPR residency: force value into accumulator register class.
__device__ __forceinline__ void agw(uint32_t &slot, uint32_t v) {
  asm volatile("v_accvgpr_write_b32 %0, %1" : "=a"(slot) : "v"(v));
}
__device__ __forceinline__ uint32_t agr(uint32_t slot) {
  uint32_t v;
  asm("v_accvgpr_read_b32 %0, %1" : "=v"(v) : "a"(slot));
  return v;
}

__global__ __launch_bounds__(TPB)
void lstm(const float* __restrict__ ctx, const float* __restrict__ u,
          const float* __restrict__ l1w, const float* __restrict__ l1b,
          const float* __restrict__ Wf,  const float* __restrict__ Wfb,
          const float* __restrict__ Wi,  const float* __restrict__ Wib,
          const float* __restrict__ Wc,  const float* __restrict__ Wcb,
          const float* __restrict__ Wow, const float* __restrict__ Wob,
          float* __restrict__ hf0, float* __restrict__ hf1,
          uint32_t* __restrict__ hh0, uint32_t* __restrict__ hh1,
          unsigned* __restrict__ cnt, float* __restrict__ out)
{
  __shared__ uint4 wlds[WAVES][HID/8];    // 1 LDS row per wave, 128 KB
  __shared__ uint4 zsh4[HID/8];           // z packed f16x2, 8 KB
  __shared__ float red[WAVES];
  __shared__ float pre[GROWS];
  __shared__ float cst[HROWS];
  __shared__ float bias[GROWS];
  __shared__ float wx[GROWS];             // column-4096 (x) weight per row
  __shared__ float x0sh;

  const int tid  = threadIdx.x;
  const int b    = blockIdx.x;
  const int wv   = tid >> 6;
  const int lane = tid & 63;

  uint32_t* z32 = (uint32_t*)zsh4;
  for (int i = tid; i < HID/2; i += TPB) z32[i] = 0u;
  if (tid < HROWS) cst[tid] = 0.f;
  if (tid < GROWS) {
    int g = tid / HROWS, j = tid % HROWS;
    const float* bw = (g==0 ? Wfb : (g==1 ? Wib : Wcb));
    const float* gw = (g==0 ? Wf  : (g==1 ? Wi  : Wc ));
    bias[tid] = bw[b*HROWS + j];
    wx[tid]   = gw[(size_t)(b*HROWS + j)*4097 + 4096];
  }

  // o-gate weights resident (step-invariant), f32
  float wow[4];
  #pragma unroll
  for (int k = 0; k < 4; ++k) wow[k] = Wow[tid + k*TPB];
  const float woxw = Wow[HID];
  const float wob0 = Wob[0];

  // load + convert this wave's 3 gate rows: 2 -> AGPRs, 1 -> LDS
  uint32_t wreg[64];    // fully unrolled access only; lives in AGPRs
  {
    const int fl0 = wv*RPW;
    const int g0 = (fl0+0)/HROWS, j0 = (fl0+0)%HROWS;
    const int g1 = (fl0+1)/HROWS, j1 = (fl0+1)%HROWS;
    const int g2 = (fl0+2)/HROWS, j2 = (fl0+2)%HROWS;
    const float* r0 = (g0==0?Wf:(g0==1?Wi:Wc)) + (size_t)(b*HROWS+j0)*4097;
    const float* r1 = (g1==0?Wf:(g1==1?Wi:Wc)) + (size_t)(b*HROWS+j1)*4097;
    const float* r2 = (g2==0?Wf:(g2==1?Wi:Wc)) + (size_t)(b*HROWS+j2)*4097;
    #pragma unroll
    for (int c = 0; c < NCH; ++c) {
      const int col = c*512 + lane*8;
      const uint4 va = cvt8(r0 + col);
      agw(wreg[c*8+0], va.x); agw(wreg[c*8+1], va.y);
      agw(wreg[c*8+2], va.z); agw(wreg[c*8+3], va.w);
      const uint4 vb = cvt8(r1 + col);
      agw(wreg[c*8+4], vb.x); agw(wreg[c*8+5], vb.y);
      agw(wreg[c*8+6], vb.z); agw(wreg[c*8+7], vb.w);
      wlds[wv][c*64 + lane] = cvt8(r2 + col);
    }
  }

  // x0 = l1_w . context + l1_b (identical in every block); CTX == TPB
  {
    float p = l1w[tid] * ctx[tid];
    #pragma unroll
    for (int off = 32; off; off >>= 1) p += __shfl_down(p, off, 64);
    __syncthreads();                 // covers zsh4 zero-init + wlds + cst
    if (lane == 0) red[wv] = p;
    __syncthreads();
    if (tid == 0) {
      float ssum = 0.f;
      for (int w = 0; w < WAVES; ++w) ssum += red[w];
      x0sh = ssum + l1b[0];
    }
    __syncthreads();
  }
  float xcur = x0sh;
  float logp = 0.f;
  float hreg[4];
  #pragma unroll
  for (int k = 0; k < 4; ++k) hreg[k] = 0.f;
  float ut = u[0];

  for (int t = 0; t < NSTEPS; ++t) {
    // ---- o-gate partial (f32, identical in all blocks); reduce hides under dots
    float p = 0.f;
    #pragma unroll
    for (int k = 0; k < 4; ++k) p = fmaf(wow[k], hreg[k], p);
    #pragma unroll
    for (int off = 32; off; off >>= 1) p += __shfl_down(p, off, 64);
    if (lane == 0) red[wv] = p;
    __syncthreads();

    // ---- f/i/c gate dots from resident weights (AGPR + LDS) ----
    float a0 = 0.f, a1 = 0.f, a2 = 0.f;
    #pragma unroll
    for (int c = 0; c < NCH; ++c) {
      const uint4 zz = zsh4[c*64 + lane];
      const uint4 wl = wlds[wv][c*64 + lane];
      a0 = fdot2f(agr(wreg[c*8+0]), zz.x, a0);
      a0 = fdot2f(agr(wreg[c*8+1]), zz.y, a0);
      a0 = fdot2f(agr(wreg[c*8+2]), zz.z, a0);
      a0 = fdot2f(agr(wreg[c*8+3]), zz.w, a0);
      a1 = fdot2f(agr(wreg[c*8+4]), zz.x, a1);
      a1 = fdot2f(agr(wreg[c*8+5]), zz.y, a1);
      a1 = fdot2f(agr(wreg[c*8+6]), zz.z, a1);
      a1 = fdot2f(agr(wreg[c*8+7]), zz.w, a1);
      a2 = dot4(a2, wl, zz);
    }
    #pragma unroll
    for (int off = 32; off; off >>= 1) {
      a0 += __shfl_down(a0, off, 64);
      a1 += __shfl_down(a1, off, 64);
      a2 += __shfl_down(a2, off, 64);
    }

    // ---- finish o-gate (identical everywhere) ----
    float osum = 0.f;
    #pragma unroll
    for (int w = 0; w < WAVES; ++w) osum += red[w];
    const float opre = osum + woxw*xcur + wob0;
    const float o = 1.f / (1.f + expf(-opre));
    const float s = (ut < o) ? 1.f : 0.f;

    if (lane == 0) {
      const int fl = wv*RPW;
      pre[fl+0] = a0 + wx[fl+0]*xcur + bias[fl+0];
      pre[fl+1] = a1 + wx[fl+1]*xcur + bias[fl+1];
      pre[fl+2] = a2 + wx[fl+2]*xcur + bias[fl+2];
    }
    __syncthreads();

    // ---- h update: all stores from wave 0 so tid0's fence covers them ----
    float* hwF = (t & 1) ? hf1 : hf0;
    uint32_t* hwH = (t & 1) ? hh1 : hh0;
    float hv = 0.f;
    if (tid < HROWS) {
      const float ff = 1.f / (1.f + expf(-pre[tid]));
      const float ii = 1.f / (1.f + expf(-pre[HROWS+tid]));
      const float cc = tanhf(pre[2*HROWS+tid]);
      const float cn = ff*cst[tid] + ii*cc;
      cst[tid] = cn;
      hv = o * tanhf(cn);
      hwF[b*HROWS + tid] = hv;
    }
    if (tid < 64) {
      const float he = __shfl(hv, 2*(tid&7),   64);
      const float ho = __shfl(hv, 2*(tid&7)+1, 64);
      if (tid < 8) hwH[b*8 + tid] = pkf16(he, ho);
    }
    if (b == 0 && tid == 0) {
      logp += (s != 0.f) ? logf(o) : logf(1.f - o);
      out[t] = s;
    }
    xcur = s;

    if (t + 1 < NSTEPS) {
      // ---- grid barrier: single counter, tid0-only publish + poll ----
      // (h stores above are all from wave 0; tid0's threadfence covers them)
      if (tid == 0) {
        __threadfence();
        __hip_atomic_fetch_add(cnt, 1u, __ATOMIC_ACQ_REL,
                               __HIP_MEMORY_SCOPE_AGENT);
        const unsigned target = (unsigned)(t+1) * NBLK;
        while (__hip_atomic_load(cnt, __ATOMIC_ACQUIRE,
                                 __HIP_MEMORY_SCOPE_AGENT) < target)
          __builtin_amdgcn_s_sleep(2);
      }
      __syncthreads();
      __builtin_amdgcn_fence(__ATOMIC_ACQUIRE, "agent");

      // ---- gather z(t): f16 to LDS for gate dots, f32 to regs for o-gate ----
      const float*    hrF = (t & 1) ? hf1 : hf0;
      const uint32_t* hr2 = (t & 1) ? hh1 : hh0;
      #pragma unroll
      for (int k = 0; k < 4; ++k) hreg[k] = hrF[tid + k*TPB];
      #pragma unroll
      for (int k = 0; k < 2; ++k) z32[tid + k*TPB] = hr2[tid + k*TPB];
      ut = u[t+1];
      __syncthreads();
    }
  }
  if (b == 0 && tid == 0) out[NSTEPS] = logp;
}

extern "C" void kernel_launch(void* const* d_in, const int* in_sizes, int n_in,
                              void* d_out, int out_size, void* d_ws, size_t ws_size,
                              hipStream_t stream) {
  const float* ctx = (const float*)d_in[0];
  const float* u   = (const float*)d_in[1];
  const float* l1w = (const float*)d_in[2];
  const float* l1b = (const float*)d_in[3];
  const float* Wf  = (const float*)d_in[4];
  const float* Wfb = (const float*)d_in[5];
  const float* Wi  = (const float*)d_in[6];
  const float* Wib = (const float*)d_in[7];
  const float* Wc  = (const float*)d_in[8];
  const float* Wcb = (const float*)d_in[9];
  const float* Wow = (const float*)d_in[10];
  const float* Wob = (const float*)d_in[11];
  float* out = (float*)d_out;

  char* ws = (char*)d_ws;
  unsigned* cnt = (unsigned*)ws;                   // memset 4 KB each launch
  float*    hf0 = (float*)(ws + 4096);
  float*    hf1 = (float*)(ws + 4096 + HID*4);
  uint32_t* hh0 = (uint32_t*)(ws + 4096 + 2*HID*4);
  uint32_t* hh1 = (uint32_t*)(ws + 4096 + 2*HID*4 + HID*2);

  (void)hipMemsetAsync(cnt, 0, 4096, stream);
  lstm<<<NBLK, TPB, 0, stream>>>(ctx,u,l1w,l1b,Wf,Wfb,Wi,Wib,Wc,Wcb,Wow,Wob,
                                 hf0,hf1,hh0,hh1,cnt,out);
}

// Round 9
// 2332.197 us; speedup vs baseline: 5.4825x; 5.4825x over previous
//
#include <hip/hip_runtime.h>
#include <hip/hip_fp16.h>
#include <stdint.h>

// LSTM policy rollout, weight-resident (AGPR), fence-free grid sync.
// 256 blocks x 1024 threads, 1 block/CU. Weights: 2 rows/wave in AGPRs
// (inline-asm "a" class, unspillable) + 1 row/wave in LDS (128 KB).
// h exchange via RELAXED agent-scope atomics (sc0/sc1: bypass L1/L2, MALL-
// coherent) -> NO buffer_inv / threadfence anywhere in the step loop.
// Rounds 5-8 showed the block-wide agent acquire fence (4096 L2-invalidates
// per step) was the 43-50 us/step floor.

#define HID    4096
#define CTX    1024
#define NSTEPS 256
#define NBLK   256
#define TPB    1024
#define WAVES  16
#define HROWS  16          // h rows per block
#define GROWS  48          // gate rows per block
#define RPW    3           // rows per wave (2 AGPR + 1 LDS)
#define NCH    8           // column chunks of 512

typedef _Float16 h2 __attribute__((ext_vector_type(2)));

__device__ __forceinline__ float fdot2f(uint32_t a, uint32_t b, float c) {
#if __has_builtin(__builtin_amdgcn_fdot2)
  return __builtin_amdgcn_fdot2(__builtin_bit_cast(h2, a),
                                __builtin_bit_cast(h2, b), c, false);
#else
  h2 x = __builtin_bit_cast(h2, a), y = __builtin_bit_cast(h2, b);
  return c + (float)x[0]*(float)y[0] + (float)x[1]*(float)y[1];
#endif
}
__device__ __forceinline__ uint32_t pkf16(float x, float y) {
  h2 v; v[0] = (_Float16)x; v[1] = (_Float16)y;
  return __builtin_bit_cast(uint32_t, v);
}
__device__ __forceinline__ uint4 cvt8(const float* p) {
  return make_uint4(pkf16(p[0],p[1]), pkf16(p[2],p[3]),
                    pkf16(p[4],p[5]), pkf16(p[6],p[7]));
}
__device__ __forceinline__ float dot4(float acc, uint4 a, uint4 b) {
  acc = fdot2f(a.x, b.x, acc); acc = fdot2f(a.y, b.y, acc);
  acc = fdot2f(a.z, b.z, acc); acc = fdot2f(a.w, b.w, acc);
  return acc;
}
// AGPR residency: force value into accumulator register class.
__device__ __forceinline__ void agw(uint32_t &slot, uint32_t v) {
  asm volatile("v_accvgpr_write_b32 %0, %1" : "=a"(slot) : "v"(v));
}
__device__ __forceinline__ uint32_t agr(uint32_t slot) {
  uint32_t v;
  asm("v_accvgpr_read_b32 %0, %1" : "=v"(v) : "a"(slot));
  return v;
}
// Coherent (MALL-level, L1/L2-bypassing) accesses for cross-block exchange.
__device__ __forceinline__ void   stF(float* p, float v) {
  __hip_atomic_store(p, v, __ATOMIC_RELAXED, __HIP_MEMORY_SCOPE_AGENT);
}
__device__ __forceinline__ float  ldF(const float* p) {
  return __hip_atomic_load(p, __ATOMIC_RELAXED, __HIP_MEMORY_SCOPE_AGENT);
}
__device__ __forceinline__ void   stU(uint32_t* p, uint32_t v) {
  __hip_atomic_store(p, v, __ATOMIC_RELAXED, __HIP_MEMORY_SCOPE_AGENT);
}
__device__ __forceinline__ uint32_t ldU(const uint32_t* p) {
  return __hip_atomic_load(p, __ATOMIC_RELAXED, __HIP_MEMORY_SCOPE_AGENT);
}

__global__ __launch_bounds__(TPB)
void lstm(const float* __restrict__ ctx, const float* __restrict__ u,
          const float* __restrict__ l1w, const float* __restrict__ l1b,
          const float* __restrict__ Wf,  const float* __restrict__ Wfb,
          const float* __restrict__ Wi,  const float* __restrict__ Wib,
          const float* __restrict__ Wc,  const float* __restrict__ Wcb,
          const float* __restrict__ Wow, const float* __restrict__ Wob,
          float* __restrict__ hf0, float* __restrict__ hf1,
          uint32_t* __restrict__ hh0, uint32_t* __restrict__ hh1,
          unsigned* __restrict__ cnt, float* __restrict__ out)
{
  __shared__ uint4 wlds[WAVES][HID/8];    // 1 LDS row per wave, 128 KB
  __shared__ uint4 zsh4[HID/8];           // z packed f16x2, 8 KB
  __shared__ float red[WAVES];
  __shared__ float pre[GROWS];
  __shared__ float cst[HROWS];
  __shared__ float bias[GROWS];
  __shared__ float wx[GROWS];             // column-4096 (x) weight per row
  __shared__ float x0sh;

  const int tid  = threadIdx.x;
  const int b    = blockIdx.x;
  const int wv   = tid >> 6;
  const int lane = tid & 63;

  uint32_t* z32 = (uint32_t*)zsh4;
  for (int i = tid; i < HID/2; i += TPB) z32[i] = 0u;
  if (tid < HROWS) cst[tid] = 0.f;
  if (tid < GROWS) {
    int g = tid / HROWS, j = tid % HROWS;
    const float* bw = (g==0 ? Wfb : (g==1 ? Wib : Wcb));
    const float* gw = (g==0 ? Wf  : (g==1 ? Wi  : Wc ));
    bias[tid] = bw[b*HROWS + j];
    wx[tid]   = gw[(size_t)(b*HROWS + j)*4097 + 4096];
  }

  // o-gate weights resident (step-invariant), f32
  float wow[4];
  #pragma unroll
  for (int k = 0; k < 4; ++k) wow[k] = Wow[tid + k*TPB];
  const float woxw = Wow[HID];
  const float wob0 = Wob[0];

  // load + convert this wave's 3 gate rows: 2 -> AGPRs, 1 -> LDS
  uint32_t wreg[64];    // fully unrolled access only; lives in AGPRs
  {
    const int fl0 = wv*RPW;
    const int g0 = (fl0+0)/HROWS, j0 = (fl0+0)%HROWS;
    const int g1 = (fl0+1)/HROWS, j1 = (fl0+1)%HROWS;
    const int g2 = (fl0+2)/HROWS, j2 = (fl0+2)%HROWS;
    const float* r0 = (g0==0?Wf:(g0==1?Wi:Wc)) + (size_t)(b*HROWS+j0)*4097;
    const float* r1 = (g1==0?Wf:(g1==1?Wi:Wc)) + (size_t)(b*HROWS+j1)*4097;
    const float* r2 = (g2==0?Wf:(g2==1?Wi:Wc)) + (size_t)(b*HROWS+j2)*4097;
    #pragma unroll
    for (int c = 0; c < NCH; ++c) {
      const int col = c*512 + lane*8;
      const uint4 va = cvt8(r0 + col);
      agw(wreg[c*8+0], va.x); agw(wreg[c*8+1], va.y);
      agw(wreg[c*8+2], va.z); agw(wreg[c*8+3], va.w);
      const uint4 vb = cvt8(r1 + col);
      agw(wreg[c*8+4], vb.x); agw(wreg[c*8+5], vb.y);
      agw(wreg[c*8+6], vb.z); agw(wreg[c*8+7], vb.w);
      wlds[wv][c*64 + lane] = cvt8(r2 + col);
    }
  }

  // x0 = l1_w . context + l1_b (identical in every block); CTX == TPB
  {
    float p = l1w[tid] * ctx[tid];
    #pragma unroll
    for (int off = 32; off; off >>= 1) p += __shfl_down(p, off, 64);
    __syncthreads();                 // covers zsh4 zero-init + wlds + cst
    if (lane == 0) red[wv] = p;
    __syncthreads();
    if (tid == 0) {
      float ssum = 0.f;
      for (int w = 0; w < WAVES; ++w) ssum += red[w];
      x0sh = ssum + l1b[0];
    }
    __syncthreads();
  }
  float xcur = x0sh;
  float logp = 0.f;
  float hreg[4];
  #pragma unroll
  for (int k = 0; k < 4; ++k) hreg[k] = 0.f;
  float ut = u[0];

  for (int t = 0; t < NSTEPS; ++t) {
    // ---- o-gate partial (f32, identical in all blocks); reduce hides under dots
    float p = 0.f;
    #pragma unroll
    for (int k = 0; k < 4; ++k) p = fmaf(wow[k], hreg[k], p);
    #pragma unroll
    for (int off = 32; off; off >>= 1) p += __shfl_down(p, off, 64);
    if (lane == 0) red[wv] = p;
    __syncthreads();

    // ---- f/i/c gate dots from resident weights (AGPR + LDS) ----
    float a0 = 0.f, a1 = 0.f, a2 = 0.f;
    #pragma unroll
    for (int c = 0; c < NCH; ++c) {
      const uint4 zz = zsh4[c*64 + lane];
      const uint4 wl = wlds[wv][c*64 + lane];
      a0 = fdot2f(agr(wreg[c*8+0]), zz.x, a0);
      a0 = fdot2f(agr(wreg[c*8+1]), zz.y, a0);
      a0 = fdot2f(agr(wreg[c*8+2]), zz.z, a0);
      a0 = fdot2f(agr(wreg[c*8+3]), zz.w, a0);
      a1 = fdot2f(agr(wreg[c*8+4]), zz.x, a1);
      a1 = fdot2f(agr(wreg[c*8+5]), zz.y, a1);
      a1 = fdot2f(agr(wreg[c*8+6]), zz.z, a1);
      a1 = fdot2f(agr(wreg[c*8+7]), zz.w, a1);
      a2 = dot4(a2, wl, zz);
    }
    #pragma unroll
    for (int off = 32; off; off >>= 1) {
      a0 += __shfl_down(a0, off, 64);
      a1 += __shfl_down(a1, off, 64);
      a2 += __shfl_down(a2, off, 64);
    }

    // ---- finish o-gate (identical everywhere) ----
    float osum = 0.f;
    #pragma unroll
    for (int w = 0; w < WAVES; ++w) osum += red[w];
    const float opre = osum + woxw*xcur + wob0;
    const float o = 1.f / (1.f + expf(-opre));
    const float s = (ut < o) ? 1.f : 0.f;

    if (lane == 0) {
      const int fl = wv*RPW;
      pre[fl+0] = a0 + wx[fl+0]*xcur + bias[fl+0];
      pre[fl+1] = a1 + wx[fl+1]*xcur + bias[fl+1];
      pre[fl+2] = a2 + wx[fl+2]*xcur + bias[fl+2];
    }
    __syncthreads();

    // ---- h update: all exchange stores from wave 0, coherent (MALL) ----
    float* hwF = (t & 1) ? hf1 : hf0;
    uint32_t* hwH = (t & 1) ? hh1 : hh0;
    float hv = 0.f;
    if (tid < HROWS) {
      const float ff = 1.f / (1.f + expf(-pre[tid]));
      const float ii = 1.f / (1.f + expf(-pre[HROWS+tid]));
      const float cc = tanhf(pre[2*HROWS+tid]);
      const float cn = ff*cst[tid] + ii*cc;
      cst[tid] = cn;
      hv = o * tanhf(cn);
      stF(&hwF[b*HROWS + tid], hv);
    }
    if (tid < 64) {
      const float he = __shfl(hv, 2*(tid&7),   64);
      const float ho = __shfl(hv, 2*(tid&7)+1, 64);
      if (tid < 8) stU(&hwH[b*8 + tid], pkf16(he, ho));
    }
    if (b == 0 && tid == 0) {
      logp += (s != 0.f) ? logf(o) : logf(1.f - o);
      out[t] = s;
    }
    xcur = s;

    if (t + 1 < NSTEPS) {
      // ---- grid barrier: release RMW (waits wave-0 vmcnt) + relaxed poll ----
      if (tid == 0) {
        __hip_atomic_fetch_add(cnt, 1u, __ATOMIC_RELEASE,
                               __HIP_MEMORY_SCOPE_AGENT);
        const unsigned target = (unsigned)(t+1) * NBLK;
        while (__hip_atomic_load(cnt, __ATOMIC_RELAXED,
                                 __HIP_MEMORY_SCOPE_AGENT) < target)
          __builtin_amdgcn_s_sleep(2);
      }
      __syncthreads();

      // ---- gather z(t) via coherent loads (no cache inv needed) ----
      const float*    hrF = (t & 1) ? hf1 : hf0;
      const uint32_t* hr2 = (t & 1) ? hh1 : hh0;
      #pragma unroll
      for (int k = 0; k < 4; ++k) hreg[k] = ldF(&hrF[tid + k*TPB]);
      #pragma unroll
      for (int k = 0; k < 2; ++k) z32[tid + k*TPB] = ldU(&hr2[tid + k*TPB]);
      ut = u[t+1];
      __syncthreads();
    }
  }
  if (b == 0 && tid == 0) out[NSTEPS] = logp;
}

extern "C" void kernel_launch(void* const* d_in, const int* in_sizes, int n_in,
                              void* d_out, int out_size, void* d_ws, size_t ws_size,
                              hipStream_t stream) {
  const float* ctx = (const float*)d_in[0];
  const float* u   = (const float*)d_in[1];
  const float* l1w = (const float*)d_in[2];
  const float* l1b = (const float*)d_in[3];
  const float* Wf  = (const float*)d_in[4];
  const float* Wfb = (const float*)d_in[5];
  const float* Wi  = (const float*)d_in[6];
  const float* Wib = (const float*)d_in[7];
  const float* Wc  = (const float*)d_in[8];
  const float* Wcb = (const float*)d_in[9];
  const float* Wow = (const float*)d_in[10];
  const float* Wob = (const float*)d_in[11];
  float* out = (float*)d_out;

  char* ws = (char*)d_ws;
  unsigned* cnt = (unsigned*)ws;                   // memset 4 KB each launch
  float*    hf0 = (float*)(ws + 4096);
  float*    hf1 = (float*)(ws + 4096 + HID*4);
  uint32_t* hh0 = (uint32_t*)(ws + 4096 + 2*HID*4);
  uint32_t* hh1 = (uint32_t*)(ws + 4096 + 2*HID*4 + HID*2);

  (void)hipMemsetAsync(cnt, 0, 4096, stream);
  lstm<<<NBLK, TPB, 0, stream>>>(ctx,u,l1w,l1b,Wf,Wfb,Wi,Wib,Wc,Wcb,Wow,Wob,
                                 hf0,hf1,hh0,hh1,cnt,out);
}

// Round 10
// 1551.840 us; speedup vs baseline: 8.2395x; 1.5029x over previous
//
#include <hip/hip_runtime.h>
#include <hip/hip_fp16.h>
#include <stdint.h>

// LSTM policy rollout, weight-resident (AGPR), fence-free MALL sync.
// 256 blocks x 1024 threads, 1 block/CU. Weights: 2 rows/wave in AGPRs
// (inline-asm "a" class) + 1 row/wave in LDS (128 KB).
// Round-9 lesson: agent acquire fences (buffer_inv) were 40 us/step; all
// cross-block exchange is RELAXED agent-scope atomics (bypass L1/L2, MALL-
// coherent). This round: (1) 8-way distributed barrier counters (one 128B
// line per 32-block group) to cut single-line RMW serialization ~8x;
// (2) o-gate via per-block partial dots (1 float/block published; wave 0
// reduces 256 partials with a fixed tree -> bit-identical o everywhere)
// instead of every thread gathering the full f32 h vector.

#define HID    4096
#define CTX    1024
#define NSTEPS 256
#define NBLK   256
#define TPB    1024
#define WAVES  16
#define HROWS  16          // h rows per block
#define GROWS  48          // gate rows per block
#define RPW    3           // rows per wave (2 AGPR + 1 LDS)
#define NCH    8           // column chunks of 512
#define NCNT   8           // distributed barrier counters
#define CLINE  32          // dwords per 128-byte line
#define GPC    (NBLK/NCNT) // blocks per counter group = 32

typedef _Float16 h2 __attribute__((ext_vector_type(2)));

__device__ __forceinline__ float fdot2f(uint32_t a, uint32_t b, float c) {
#if __has_builtin(__builtin_amdgcn_fdot2)
  return __builtin_amdgcn_fdot2(__builtin_bit_cast(h2, a),
                                __builtin_bit_cast(h2, b), c, false);
#else
  h2 x = __builtin_bit_cast(h2, a), y = __builtin_bit_cast(h2, b);
  return c + (float)x[0]*(float)y[0] + (float)x[1]*(float)y[1];
#endif
}
__device__ __forceinline__ uint32_t pkf16(float x, float y) {
  h2 v; v[0] = (_Float16)x; v[1] = (_Float16)y;
  return __builtin_bit_cast(uint32_t, v);
}
__device__ __forceinline__ uint4 cvt8(const float* p) {
  return make_uint4(pkf16(p[0],p[1]), pkf16(p[2],p[3]),
                    pkf16(p[4],p[5]), pkf16(p[6],p[7]));
}
__device__ __forceinline__ float dot4(float acc, uint4 a, uint4 b) {
  acc = fdot2f(a.x, b.x, acc); acc = fdot2f(a.y, b.y, acc);
  acc = fdot2f(a.z, b.z, acc); acc = fdot2f(a.w, b.w, acc);
  return acc;
}
// AGPR residency: force value into accumulator register class.
__device__ __forceinline__ void agw(uint32_t &slot, uint32_t v) {
  asm volatile("v_accvgpr_write_b32 %0, %1" : "=a"(slot) : "v"(v));
}
__device__ __forceinline__ uint32_t agr(uint32_t slot) {
  uint32_t v;
  asm("v_accvgpr_read_b32 %0, %1" : "=v"(v) : "a"(slot));
  return v;
}
// Coherent (MALL-level, L1/L2-bypassing) accesses for cross-block exchange.
__device__ __forceinline__ void   stF(float* p, float v) {
  __hip_atomic_store(p, v, __ATOMIC_RELAXED, __HIP_MEMORY_SCOPE_AGENT);
}
__device__ __forceinline__ float  ldF(const float* p) {
  return __hip_atomic_load(p, __ATOMIC_RELAXED, __HIP_MEMORY_SCOPE_AGENT);
}
__device__ __forceinline__ void   stU(uint32_t* p, uint32_t v) {
  __hip_atomic_store(p, v, __ATOMIC_RELAXED, __HIP_MEMORY_SCOPE_AGENT);
}
__device__ __forceinline__ uint32_t ldU(const uint32_t* p) {
  return __hip_atomic_load(p, __ATOMIC_RELAXED, __HIP_MEMORY_SCOPE_AGENT);
}

__global__ __launch_bounds__(TPB)
void lstm(const float* __restrict__ ctx, const float* __restrict__ u,
          const float* __restrict__ l1w, const float* __restrict__ l1b,
          const float* __restrict__ Wf,  const float* __restrict__ Wfb,
          const float* __restrict__ Wi,  const float* __restrict__ Wib,
          const float* __restrict__ Wc,  const float* __restrict__ Wcb,
          const float* __restrict__ Wow, const float* __restrict__ Wob,
          uint32_t* __restrict__ hh0, uint32_t* __restrict__ hh1,
          float* __restrict__ part0, float* __restrict__ part1,
          unsigned* __restrict__ cnt8, float* __restrict__ out)
{
  __shared__ uint4 wlds[WAVES][HID/8];    // 1 LDS row per wave, 128 KB
  __shared__ uint4 zsh4[HID/8];           // z packed f16x2, 8 KB
  __shared__ float red[WAVES];
  __shared__ float pre[GROWS];
  __shared__ float cst[HROWS];
  __shared__ float bias[GROWS];
  __shared__ float wx[GROWS];             // column-4096 (x) weight per row
  __shared__ float x0sh, osh, ssh;

  const int tid  = threadIdx.x;
  const int b    = blockIdx.x;
  const int wv   = tid >> 6;
  const int lane = tid & 63;

  uint32_t* z32 = (uint32_t*)zsh4;
  for (int i = tid; i < HID/2; i += TPB) z32[i] = 0u;
  if (tid < HROWS) cst[tid] = 0.f;
  if (tid < GROWS) {
    int g = tid / HROWS, j = tid % HROWS;
    const float* bw = (g==0 ? Wfb : (g==1 ? Wib : Wcb));
    const float* gw = (g==0 ? Wf  : (g==1 ? Wi  : Wc ));
    bias[tid] = bw[b*HROWS + j];
    wx[tid]   = gw[(size_t)(b*HROWS + j)*4097 + 4096];
  }

  // per-row o-gate weight for this block's h rows (tid<16, wave 0)
  const float wolocal = (tid < HROWS) ? Wow[b*HROWS + tid] : 0.f;
  const float woxw = Wow[HID];
  const float wob0 = Wob[0];

  // load + convert this wave's 3 gate rows: 2 -> AGPRs, 1 -> LDS
  uint32_t wreg[64];    // fully unrolled access only; lives in AGPRs
  {
    const int fl0 = wv*RPW;
    const int g0 = (fl0+0)/HROWS, j0 = (fl0+0)%HROWS;
    const int g1 = (fl0+1)/HROWS, j1 = (fl0+1)%HROWS;
    const int g2 = (fl0+2)/HROWS, j2 = (fl0+2)%HROWS;
    const float* r0 = (g0==0?Wf:(g0==1?Wi:Wc)) + (size_t)(b*HROWS+j0)*4097;
    const float* r1 = (g1==0?Wf:(g1==1?Wi:Wc)) + (size_t)(b*HROWS+j1)*4097;
    const float* r2 = (g2==0?Wf:(g2==1?Wi:Wc)) + (size_t)(b*HROWS+j2)*4097;
    #pragma unroll
    for (int c = 0; c < NCH; ++c) {
      const int col = c*512 + lane*8;
      const uint4 va = cvt8(r0 + col);
      agw(wreg[c*8+0], va.x); agw(wreg[c*8+1], va.y);
      agw(wreg[c*8+2], va.z); agw(wreg[c*8+3], va.w);
      const uint4 vb = cvt8(r1 + col);
      agw(wreg[c*8+4], vb.x); agw(wreg[c*8+5], vb.y);
      agw(wreg[c*8+6], vb.z); agw(wreg[c*8+7], vb.w);
      wlds[wv][c*64 + lane] = cvt8(r2 + col);
    }
  }

  // x0 = l1_w . context + l1_b (identical in every block); CTX == TPB
  {
    float p = l1w[tid] * ctx[tid];
    #pragma unroll
    for (int off = 32; off; off >>= 1) p += __shfl_down(p, off, 64);
    __syncthreads();                 // covers zsh4 zero-init + wlds + cst
    if (lane == 0) red[wv] = p;
    __syncthreads();
    if (tid == 0) {
      float ssum = 0.f;
      for (int w = 0; w < WAVES; ++w) ssum += red[w];
      x0sh = ssum + l1b[0];
    }
    __syncthreads();
  }
  float xcur = x0sh;
  float logp = 0.f;
  float ut = u[0];

  for (int t = 0; t < NSTEPS; ++t) {
    // ---- wave 0: o-gate from 256 published partials (fixed reduction tree,
    //      bit-identical in every block); overlaps waves 1-15's dots ----
    if (wv == 0) {
      float ps = 0.f;
      if (t > 0) {
        const float* pr = (t & 1) ? part0 : part1;   // written at step t-1
        float q0 = ldF(&pr[lane*4+0]), q1 = ldF(&pr[lane*4+1]);
        float q2 = ldF(&pr[lane*4+2]), q3 = ldF(&pr[lane*4+3]);
        ps = ((q0 + q1) + q2) + q3;
      }
      #pragma unroll
      for (int off = 32; off; off >>= 1) ps += __shfl_down(ps, off, 64);
      if (lane == 0) {
        const float opre = ps + woxw*xcur + wob0;
        const float o = 1.f / (1.f + expf(-opre));
        osh = o;
        ssh = (ut < o) ? 1.f : 0.f;
      }
    }

    // ---- f/i/c gate dots from resident weights (AGPR + LDS) ----
    float a0 = 0.f, a1 = 0.f, a2 = 0.f;
    #pragma unroll
    for (int c = 0; c < NCH; ++c) {
      const uint4 zz = zsh4[c*64 + lane];
      const uint4 wl = wlds[wv][c*64 + lane];
      a0 = fdot2f(agr(wreg[c*8+0]), zz.x, a0);
      a0 = fdot2f(agr(wreg[c*8+1]), zz.y, a0);
      a0 = fdot2f(agr(wreg[c*8+2]), zz.z, a0);
      a0 = fdot2f(agr(wreg[c*8+3]), zz.w, a0);
      a1 = fdot2f(agr(wreg[c*8+4]), zz.x, a1);
      a1 = fdot2f(agr(wreg[c*8+5]), zz.y, a1);
      a1 = fdot2f(agr(wreg[c*8+6]), zz.z, a1);
      a1 = fdot2f(agr(wreg[c*8+7]), zz.w, a1);
      a2 = dot4(a2, wl, zz);
    }
    #pragma unroll
    for (int off = 32; off; off >>= 1) {
      a0 += __shfl_down(a0, off, 64);
      a1 += __shfl_down(a1, off, 64);
      a2 += __shfl_down(a2, off, 64);
    }
    if (lane == 0) {
      const int fl = wv*RPW;
      pre[fl+0] = a0 + wx[fl+0]*xcur + bias[fl+0];
      pre[fl+1] = a1 + wx[fl+1]*xcur + bias[fl+1];
      pre[fl+2] = a2 + wx[fl+2]*xcur + bias[fl+2];
    }
    __syncthreads();

    // ---- h update (wave 0 only does all exchange stores) ----
    const float o = osh;
    const float s = ssh;
    uint32_t* hwH = (t & 1) ? hh1 : hh0;
    float*    pwF = (t & 1) ? part1 : part0;
    float hv = 0.f;
    if (tid < HROWS) {
      const float ff = 1.f / (1.f + expf(-pre[tid]));
      const float ii = 1.f / (1.f + expf(-pre[HROWS+tid]));
      const float cc = tanhf(pre[2*HROWS+tid]);
      const float cn = ff*cst[tid] + ii*cc;
      cst[tid] = cn;
      hv = o * tanhf(cn);
    }
    if (tid < 64) {
      // partial o-dot over this block's 16 h values (deterministic 16-lane tree)
      float pp = wolocal * hv;      // zero for lanes 16-63
      #pragma unroll
      for (int off = 8; off; off >>= 1) pp += __shfl_down(pp, off, 64);
      const float he = __shfl(hv, 2*(tid&7),   64);
      const float ho = __shfl(hv, 2*(tid&7)+1, 64);
      if (tid < 8) stU(&hwH[b*8 + tid], pkf16(he, ho));
      if (tid == 0) stF(&pwF[b], pp);
    }
    if (b == 0 && tid == 0) {
      logp += (s != 0.f) ? logf(o) : logf(1.f - o);
      out[t] = s;
    }
    xcur = s;

    if (t + 1 < NSTEPS) {
      // ---- grid barrier: 8 distributed padded counters, release RMW ----
      if (tid == 0)
        __hip_atomic_fetch_add(&cnt8[(b & (NCNT-1)) * CLINE], 1u,
                               __ATOMIC_RELEASE, __HIP_MEMORY_SCOPE_AGENT);
      if (tid < NCNT) {
        const unsigned target = (unsigned)(t+1) * GPC;
        while (__hip_atomic_load(&cnt8[tid * CLINE], __ATOMIC_RELAXED,
                                 __HIP_MEMORY_SCOPE_AGENT) < target)
          __builtin_amdgcn_s_sleep(1);
      }
      __syncthreads();

      // ---- gather z(t) f16 via coherent loads (2 per thread) ----
      const uint32_t* hr2 = (t & 1) ? hh1 : hh0;
      #pragma unroll
      for (int k = 0; k < 2; ++k) z32[tid + k*TPB] = ldU(&hr2[tid + k*TPB]);
      ut = u[t+1];
      __syncthreads();
    }
  }
  if (b == 0 && tid == 0) out[NSTEPS] = logp;
}

extern "C" void kernel_launch(void* const* d_in, const int* in_sizes, int n_in,
                              void* d_out, int out_size, void* d_ws, size_t ws_size,
                              hipStream_t stream) {
  const float* ctx = (const float*)d_in[0];
  const float* u   = (const float*)d_in[1];
  const float* l1w = (const float*)d_in[2];
  const float* l1b = (const float*)d_in[3];
  const float* Wf  = (const float*)d_in[4];
  const float* Wfb = (const float*)d_in[5];
  const float* Wi  = (const float*)d_in[6];
  const float* Wib = (const float*)d_in[7];
  const float* Wc  = (const float*)d_in[8];
  const float* Wcb = (const float*)d_in[9];
  const float* Wow = (const float*)d_in[10];
  const float* Wob = (const float*)d_in[11];
  float* out = (float*)d_out;

  char* ws = (char*)d_ws;
  unsigned* cnt8  = (unsigned*)ws;                 // 8 lines, memset each launch
  float*    part0 = (float*)(ws + 4096);           // 256 floats
  float*    part1 = (float*)(ws + 8192);
  uint32_t* hh0   = (uint32_t*)(ws + 12288);       // HID/2 u32 = 8 KB
  uint32_t* hh1   = (uint32_t*)(ws + 12288 + 8192);

  (void)hipMemsetAsync(cnt8, 0, 4096, stream);
  lstm<<<NBLK, TPB, 0, stream>>>(ctx,u,l1w,l1b,Wf,Wfb,Wi,Wib,Wc,Wcb,Wow,Wob,
                                 hh0,hh1,part0,part1,cnt8,out);
}

// Round 11
// 1008.085 us; speedup vs baseline: 12.6838x; 1.5394x over previous
//
#include <hip/hip_runtime.h>
#include <hip/hip_fp16.h>
#include <stdint.h>

// LSTM policy rollout, weight-resident (AGPR), barrier-free tagged-data sync.
// 256 blocks x 1024 threads, 1 block/CU. Weights: 2 rows/wave in AGPRs
// (inline-asm "a" class) + 1 row/wave in LDS (128 KB).
// Cross-block exchange: h (f16x2) and o-partials published as {payload,epoch}
// uint64 via RELAXED agent-scope atomics (MALL-coherent, no L2 invalidates).
// Consumers poll the tag of the exact word they need -> flag wait + data load
// fused into ONE MALL round trip; no counters, no RMWs, no fences.
// Epoch parity double-buffer; publish(t+2) provably cannot overwrite an
// unconsumed epoch-t word (publish requires full gather of t+1 first).

#define HID    4096
#define CTX    1024
#define NSTEPS 256
#define NBLK   256
#define TPB    1024
#define WAVES  16
#define HROWS  16          // h rows per block
#define GROWS  48          // gate rows per block
#define RPW    3           // rows per wave (2 AGPR + 1 LDS)
#define NCH    8           // column chunks of 512

typedef _Float16 h2 __attribute__((ext_vector_type(2)));

__device__ __forceinline__ float fdot2f(uint32_t a, uint32_t b, float c) {
#if __has_builtin(__builtin_amdgcn_fdot2)
  return __builtin_amdgcn_fdot2(__builtin_bit_cast(h2, a),
                                __builtin_bit_cast(h2, b), c, false);
#else
  h2 x = __builtin_bit_cast(h2, a), y = __builtin_bit_cast(h2, b);
  return c + (float)x[0]*(float)y[0] + (float)x[1]*(float)y[1];
#endif
}
__device__ __forceinline__ uint32_t pkf16(float x, float y) {
  h2 v; v[0] = (_Float16)x; v[1] = (_Float16)y;
  return __builtin_bit_cast(uint32_t, v);
}
__device__ __forceinline__ uint4 cvt8(const float* p) {
  return make_uint4(pkf16(p[0],p[1]), pkf16(p[2],p[3]),
                    pkf16(p[4],p[5]), pkf16(p[6],p[7]));
}
__device__ __forceinline__ float dot4(float acc, uint4 a, uint4 b) {
  acc = fdot2f(a.x, b.x, acc); acc = fdot2f(a.y, b.y, acc);
  acc = fdot2f(a.z, b.z, acc); acc = fdot2f(a.w, b.w, acc);
  return acc;
}
// AGPR residency: force value into accumulator register class.
__device__ __forceinline__ void agw(uint32_t &slot, uint32_t v) {
  asm volatile("v_accvgpr_write_b32 %0, %1" : "=a"(slot) : "v"(v));
}
__device__ __forceinline__ uint32_t agr(uint32_t slot) {
  uint32_t v;
  asm("v_accvgpr_read_b32 %0, %1" : "=v"(v) : "a"(slot));
  return v;
}
// Coherent (MALL-level) 64-bit tagged exchange.
__device__ __forceinline__ void stT(uint64_t* p, uint32_t payload, uint32_t tag) {
  const uint64_t v = ((uint64_t)tag << 32) | (uint64_t)payload;
  __hip_atomic_store(p, v, __ATOMIC_RELAXED, __HIP_MEMORY_SCOPE_AGENT);
}
__device__ __forceinline__ uint64_t ldT(const uint64_t* p) {
  return __hip_atomic_load(p, __ATOMIC_RELAXED, __HIP_MEMORY_SCOPE_AGENT);
}
__device__ __forceinline__ uint32_t waitT(const uint64_t* p, uint32_t tag) {
  uint64_t v = ldT(p);
  while ((uint32_t)(v >> 32) != tag) {
    __builtin_amdgcn_s_sleep(1);
    v = ldT(p);
  }
  return (uint32_t)v;
}

__global__ __launch_bounds__(TPB)
void lstm(const float* __restrict__ ctx, const float* __restrict__ u,
          const float* __restrict__ l1w, const float* __restrict__ l1b,
          const float* __restrict__ Wf,  const float* __restrict__ Wfb,
          const float* __restrict__ Wi,  const float* __restrict__ Wib,
          const float* __restrict__ Wc,  const float* __restrict__ Wcb,
          const float* __restrict__ Wow, const float* __restrict__ Wob,
          uint64_t* __restrict__ hh0, uint64_t* __restrict__ hh1,
          uint64_t* __restrict__ part0, uint64_t* __restrict__ part1,
          float* __restrict__ out)
{
  __shared__ uint4 wlds[WAVES][HID/8];    // 1 LDS row per wave, 128 KB
  __shared__ uint4 zsh4[HID/8];           // z packed f16x2, 8 KB
  __shared__ float red[WAVES];
  __shared__ float pre[GROWS];
  __shared__ float cst[HROWS];
  __shared__ float bias[GROWS];
  __shared__ float wx[GROWS];             // column-4096 (x) weight per row
  __shared__ float x0sh, osh, ssh;

  const int tid  = threadIdx.x;
  const int b    = blockIdx.x;
  const int wv   = tid >> 6;
  const int lane = tid & 63;

  uint32_t* z32 = (uint32_t*)zsh4;
  for (int i = tid; i < HID/2; i += TPB) z32[i] = 0u;
  if (tid < HROWS) cst[tid] = 0.f;
  if (tid < GROWS) {
    int g = tid / HROWS, j = tid % HROWS;
    const float* bw = (g==0 ? Wfb : (g==1 ? Wib : Wcb));
    const float* gw = (g==0 ? Wf  : (g==1 ? Wi  : Wc ));
    bias[tid] = bw[b*HROWS + j];
    wx[tid]   = gw[(size_t)(b*HROWS + j)*4097 + 4096];
  }

  // per-row o-gate weight for this block's h rows (tid<16, wave 0)
  const float wolocal = (tid < HROWS) ? Wow[b*HROWS + tid] : 0.f;
  const float woxw = Wow[HID];
  const float wob0 = Wob[0];

  // load + convert this wave's 3 gate rows: 2 -> AGPRs, 1 -> LDS
  uint32_t wreg[64];    // fully unrolled access only; lives in AGPRs
  {
    const int fl0 = wv*RPW;
    const int g0 = (fl0+0)/HROWS, j0 = (fl0+0)%HROWS;
    const int g1 = (fl0+1)/HROWS, j1 = (fl0+1)%HROWS;
    const int g2 = (fl0+2)/HROWS, j2 = (fl0+2)%HROWS;
    const float* r0 = (g0==0?Wf:(g0==1?Wi:Wc)) + (size_t)(b*HROWS+j0)*4097;
    const float* r1 = (g1==0?Wf:(g1==1?Wi:Wc)) + (size_t)(b*HROWS+j1)*4097;
    const float* r2 = (g2==0?Wf:(g2==1?Wi:Wc)) + (size_t)(b*HROWS+j2)*4097;
    #pragma unroll
    for (int c = 0; c < NCH; ++c) {
      const int col = c*512 + lane*8;
      const uint4 va = cvt8(r0 + col);
      agw(wreg[c*8+0], va.x); agw(wreg[c*8+1], va.y);
      agw(wreg[c*8+2], va.z); agw(wreg[c*8+3], va.w);
      const uint4 vb = cvt8(r1 + col);
      agw(wreg[c*8+4], vb.x); agw(wreg[c*8+5], vb.y);
      agw(wreg[c*8+6], vb.z); agw(wreg[c*8+7], vb.w);
      wlds[wv][c*64 + lane] = cvt8(r2 + col);
    }
  }

  // x0 = l1_w . context + l1_b (identical in every block); CTX == TPB
  {
    float p = l1w[tid] * ctx[tid];
    #pragma unroll
    for (int off = 32; off; off >>= 1) p += __shfl_down(p, off, 64);
    __syncthreads();                 // covers zsh4 zero-init + wlds + cst
    if (lane == 0) red[wv] = p;
    __syncthreads();
    if (tid == 0) {
      float ssum = 0.f;
      for (int w = 0; w < WAVES; ++w) ssum += red[w];
      x0sh = ssum + l1b[0];
    }
    __syncthreads();
  }
  float xcur = x0sh;
  float logp = 0.f;
  float ut = u[0];

  for (int t = 0; t < NSTEPS; ++t) {
    // ---- wave 0: o-gate from 256 tagged partials (tag == t, written at t-1);
    //      fixed reduction tree -> bit-identical o in every block; overlaps
    //      waves 1-15's gate dots ----
    if (wv == 0) {
      float ps = 0.f;
      if (t > 0) {
        const uint64_t* pr = (t & 1) ? part0 : part1;   // written at step t-1
        const uint32_t tg = (uint32_t)t;
        const float q0 = __uint_as_float(waitT(&pr[lane*4+0], tg));
        const float q1 = __uint_as_float(waitT(&pr[lane*4+1], tg));
        const float q2 = __uint_as_float(waitT(&pr[lane*4+2], tg));
        const float q3 = __uint_as_float(waitT(&pr[lane*4+3], tg));
        ps = ((q0 + q1) + q2) + q3;
      }
      #pragma unroll
      for (int off = 32; off; off >>= 1) ps += __shfl_down(ps, off, 64);
      if (lane == 0) {
        const float opre = ps + woxw*xcur + wob0;
        const float o = 1.f / (1.f + expf(-opre));
        osh = o;
        ssh = (ut < o) ? 1.f : 0.f;
      }
    }

    // ---- f/i/c gate dots from resident weights (AGPR + LDS) ----
    float a0 = 0.f, a1 = 0.f, a2 = 0.f;
    #pragma unroll
    for (int c = 0; c < NCH; ++c) {
      const uint4 zz = zsh4[c*64 + lane];
      const uint4 wl = wlds[wv][c*64 + lane];
      a0 = fdot2f(agr(wreg[c*8+0]), zz.x, a0);
      a0 = fdot2f(agr(wreg[c*8+1]), zz.y, a0);
      a0 = fdot2f(agr(wreg[c*8+2]), zz.z, a0);
      a0 = fdot2f(agr(wreg[c*8+3]), zz.w, a0);
      a1 = fdot2f(agr(wreg[c*8+4]), zz.x, a1);
      a1 = fdot2f(agr(wreg[c*8+5]), zz.y, a1);
      a1 = fdot2f(agr(wreg[c*8+6]), zz.z, a1);
      a1 = fdot2f(agr(wreg[c*8+7]), zz.w, a1);
      a2 = dot4(a2, wl, zz);
    }
    #pragma unroll
    for (int off = 32; off; off >>= 1) {
      a0 += __shfl_down(a0, off, 64);
      a1 += __shfl_down(a1, off, 64);
      a2 += __shfl_down(a2, off, 64);
    }
    if (lane == 0) {
      const int fl = wv*RPW;
      pre[fl+0] = a0 + wx[fl+0]*xcur + bias[fl+0];
      pre[fl+1] = a1 + wx[fl+1]*xcur + bias[fl+1];
      pre[fl+2] = a2 + wx[fl+2]*xcur + bias[fl+2];
    }
    __syncthreads();   // pre[] + osh/ssh visible to all

    // ---- h update; wave 0 publishes tagged h + partial (epoch t+1) ----
    const float o = osh;
    const float s = ssh;
    uint64_t* hwH = (t & 1) ? hh1 : hh0;
    uint64_t* pwF = (t & 1) ? part1 : part0;
    float hv = 0.f;
    if (tid < HROWS) {
      const float ff = 1.f / (1.f + expf(-pre[tid]));
      const float ii = 1.f / (1.f + expf(-pre[HROWS+tid]));
      const float cc = tanhf(pre[2*HROWS+tid]);
      const float cn = ff*cst[tid] + ii*cc;
      cst[tid] = cn;
      hv = o * tanhf(cn);
    }
    if (tid < 64) {
      // partial o-dot over this block's 16 h values (deterministic tree)
      float pp = wolocal * hv;      // zero for lanes 16-63
      #pragma unroll
      for (int off = 8; off; off >>= 1) pp += __shfl_down(pp, off, 64);
      const float he = __shfl(hv, 2*(tid&7),   64);
      const float ho = __shfl(hv, 2*(tid&7)+1, 64);
      if (tid < 8) stT(&hwH[b*8 + tid], pkf16(he, ho), (uint32_t)(t+1));
      if (tid == 0) stT(&pwF[b], __float_as_uint(pp), (uint32_t)(t+1));
    }
    if (b == 0 && tid == 0) {
      logp += (s != 0.f) ? logf(o) : logf(1.f - o);
      out[t] = s;
    }
    xcur = s;

    if (t + 1 < NSTEPS) {
      // ---- gather z(t): poll the tagged words directly (one round trip) ----
      const uint64_t* hr2 = (t & 1) ? hh1 : hh0;
      const uint32_t tg = (uint32_t)(t+1);
      uint64_t v0 = ldT(&hr2[tid]);
      uint64_t v1 = ldT(&hr2[tid + TPB]);
      while ((uint32_t)(v0 >> 32) != tg) {
        __builtin_amdgcn_s_sleep(1); v0 = ldT(&hr2[tid]);
      }
      while ((uint32_t)(v1 >> 32) != tg) {
        __builtin_amdgcn_s_sleep(1); v1 = ldT(&hr2[tid + TPB]);
      }
      z32[tid]       = (uint32_t)v0;
      z32[tid + TPB] = (uint32_t)v1;
      ut = u[t+1];
      __syncthreads();
    }
  }
  if (b == 0 && tid == 0) out[NSTEPS] = logp;
}

extern "C" void kernel_launch(void* const* d_in, const int* in_sizes, int n_in,
                              void* d_out, int out_size, void* d_ws, size_t ws_size,
                              hipStream_t stream) {
  const float* ctx = (const float*)d_in[0];
  const float* u   = (const float*)d_in[1];
  const float* l1w = (const float*)d_in[2];
  const float* l1b = (const float*)d_in[3];
  const float* Wf  = (const float*)d_in[4];
  const float* Wfb = (const float*)d_in[5];
  const float* Wi  = (const float*)d_in[6];
  const float* Wib = (const float*)d_in[7];
  const float* Wc  = (const float*)d_in[8];
  const float* Wcb = (const float*)d_in[9];
  const float* Wow = (const float*)d_in[10];
  const float* Wob = (const float*)d_in[11];
  float* out = (float*)d_out;

  char* ws = (char*)d_ws;
  uint64_t* part0 = (uint64_t*)(ws + 4096);            // 256*8B = 2 KB
  uint64_t* part1 = (uint64_t*)(ws + 8192);            // 2 KB
  uint64_t* hh0   = (uint64_t*)(ws + 12288);           // 2048*8B = 16 KB
  uint64_t* hh1   = (uint64_t*)(ws + 12288 + 16384);   // 16 KB
  // zero all tags each launch (epochs are 1..256; 0 == invalid)
  (void)hipMemsetAsync(ws + 4096, 0, 40960, stream);

  lstm<<<NBLK, TPB, 0, stream>>>(ctx,u,l1w,l1b,Wf,Wfb,Wi,Wib,Wc,Wcb,Wow,Wob,
                                 hh0,hh1,part0,part1,out);
}